// Round 1
// baseline (230.019 us; speedup 1.0000x reference)
//
#include <hip/hip_runtime.h>
#include <hip/hip_fp16.h>

typedef _Float16 f16;
typedef __attribute__((ext_vector_type(8))) _Float16 half8;
typedef __attribute__((ext_vector_type(4))) float floatx4;

static constexpr int DIM = 1024;
static constexpr int SEQ = 2048;
static constexpr int DH = 64;
static constexpr int MTOT = 4096;  // BATCH * SEQ

// ---- weight transpose + fp16 convert: wt[z][n][k] = W_z[k][n] ----
__global__ __launch_bounds__(256) void k_transpose(
    const float* __restrict__ Wq, const float* __restrict__ Wk,
    const float* __restrict__ Wv, const float* __restrict__ Wo,
    f16* __restrict__ wt)
{
  __shared__ float tile[32][33];
  const int z = blockIdx.z;
  const float* W = (z == 0) ? Wq : (z == 1) ? Wk : (z == 2) ? Wv : Wo;
  f16* out = wt + (size_t)z * DIM * DIM;
  const int tx = threadIdx.x, ty = threadIdx.y;
  const int x0 = blockIdx.x * 32, y0 = blockIdx.y * 32;
#pragma unroll
  for (int i = 0; i < 4; ++i)
    tile[ty + i * 8][tx] = W[(size_t)(y0 + ty + i * 8) * DIM + (x0 + tx)];
  __syncthreads();
#pragma unroll
  for (int i = 0; i < 4; ++i)
    out[(size_t)(x0 + ty + i * 8) * DIM + (y0 + tx)] = (f16)tile[tx][ty + i * 8];
}

// ---- 128x128-tile fp16 MFMA GEMM: C = A * BT^T (+bias) ----
// A: [M][K] (fp32 or fp16), BT: [N][K] fp16, C: [M][N]
template <bool A_F32, bool OUT_F32>
__global__ __launch_bounds__(256) void k_gemm128(
    const void* __restrict__ Aptr, const f16* __restrict__ BT,
    void* __restrict__ Cptr, const float* __restrict__ bias,
    int M, int N, int K, size_t bt_zstride, size_t c_zstride)
{
  __shared__ f16 As[128][40];  // +8 pad: conflict-free ds_read_b128
  __shared__ f16 Bs[128][40];

  const int tid = threadIdx.x;
  const int lane = tid & 63;
  const int wid = tid >> 6;
  const int wr = (wid >> 1) * 64, wc = (wid & 1) * 64;
  const int li = lane & 15, lg = lane >> 4;

  const f16* BTz = BT + (size_t)blockIdx.z * bt_zstride;
  const int row0 = blockIdx.x * 128, col0 = blockIdx.y * 128;
  const int srow = tid >> 1;
  const int shalf = (tid & 1) * 16;

  const floatx4 zero4 = {0.f, 0.f, 0.f, 0.f};
  floatx4 acc[4][4];
#pragma unroll
  for (int m = 0; m < 4; ++m)
#pragma unroll
    for (int n = 0; n < 4; ++n) acc[m][n] = zero4;

  for (int k0 = 0; k0 < K; k0 += 32) {
    __syncthreads();
    if constexpr (A_F32) {
      const float* A = (const float*)Aptr;
      const float4* src = (const float4*)(A + (size_t)(row0 + srow) * K + k0 + shalf);
      float4 v0 = src[0], v1 = src[1], v2 = src[2], v3 = src[3];
      half8 h0 = {(f16)v0.x, (f16)v0.y, (f16)v0.z, (f16)v0.w,
                  (f16)v1.x, (f16)v1.y, (f16)v1.z, (f16)v1.w};
      half8 h1 = {(f16)v2.x, (f16)v2.y, (f16)v2.z, (f16)v2.w,
                  (f16)v3.x, (f16)v3.y, (f16)v3.z, (f16)v3.w};
      *(half8*)&As[srow][shalf] = h0;
      *(half8*)&As[srow][shalf + 8] = h1;
    } else {
      const f16* A = (const f16*)Aptr;
      const f16* src = A + (size_t)(row0 + srow) * K + k0 + shalf;
      *(half8*)&As[srow][shalf] = *(const half8*)src;
      *(half8*)&As[srow][shalf + 8] = *(const half8*)(src + 8);
    }
    {
      const f16* src = BTz + (size_t)(col0 + srow) * K + k0 + shalf;
      *(half8*)&Bs[srow][shalf] = *(const half8*)src;
      *(half8*)&Bs[srow][shalf + 8] = *(const half8*)(src + 8);
    }
    __syncthreads();

    half8 af[4], bf[4];
#pragma unroll
    for (int m = 0; m < 4; ++m)
      af[m] = *(const half8*)&As[wr + m * 16 + li][lg * 8];
#pragma unroll
    for (int n = 0; n < 4; ++n)
      bf[n] = *(const half8*)&Bs[wc + n * 16 + li][lg * 8];
#pragma unroll
    for (int m = 0; m < 4; ++m)
#pragma unroll
      for (int n = 0; n < 4; ++n)
        acc[m][n] = __builtin_amdgcn_mfma_f32_16x16x32_f16(af[m], bf[n], acc[m][n], 0, 0, 0);
  }

#pragma unroll
  for (int m = 0; m < 4; ++m)
#pragma unroll
    for (int n = 0; n < 4; ++n)
#pragma unroll
      for (int r = 0; r < 4; ++r) {
        const int row = row0 + wr + m * 16 + lg * 4 + r;
        const int col = col0 + wc + n * 16 + li;
        if constexpr (OUT_F32) {
          float* C = (float*)Cptr + (size_t)blockIdx.z * c_zstride;
          C[(size_t)row * N + col] = acc[m][n][r] + bias[col];
        } else {
          f16* C = (f16*)Cptr + (size_t)blockIdx.z * c_zstride;
          C[(size_t)row * N + col] = (f16)acc[m][n][r];
        }
      }
}

// ---- flash attention: per (b,h), 64 q-rows/block, KV tiles of 64 ----
__global__ __launch_bounds__(256) void k_attn(
    const f16* __restrict__ qh, const f16* __restrict__ kh,
    const f16* __restrict__ vh, f16* __restrict__ oh)
{
  __shared__ f16 Vt[64][72];      // V^T tile: [d][kv], pad 72 for b128 reads
  __shared__ f16 Pl[4][16][72];   // per-wave P transpose: [qrow][kv]

  const int tid = threadIdx.x;
  const int lane = tid & 63;
  const int wid = tid >> 6;
  const int li = lane & 15, lg = lane >> 4;
  const int b = blockIdx.y >> 4, h = blockIdx.y & 15;
  const int q0 = blockIdx.x * 64 + wid * 16;

  const size_t base = (size_t)b * SEQ * DIM + (size_t)h * DH;

  half8 qa0, qa1;
  {
    const f16* qrow = qh + base + (size_t)(q0 + li) * DIM;
    qa0 = *(const half8*)(qrow + lg * 8);
    qa1 = *(const half8*)(qrow + 32 + lg * 8);
  }

  const floatx4 zero4 = {0.f, 0.f, 0.f, 0.f};
  float mrow[4], lsum[4];
  floatx4 o[4];
#pragma unroll
  for (int r = 0; r < 4; ++r) { mrow[r] = -1e30f; lsum[r] = 0.f; }
#pragma unroll
  for (int dt = 0; dt < 4; ++dt) o[dt] = zero4;

  for (int kt = 0; kt < SEQ; kt += 64) {
    __syncthreads();
    {  // stage V transposed
      const int kv = tid >> 2;
      const int dq = (tid & 3) * 16;
      const f16* vrow = vh + base + (size_t)(kt + kv) * DIM + dq;
      half8 v0 = *(const half8*)vrow;
      half8 v1 = *(const half8*)(vrow + 8);
#pragma unroll
      for (int j = 0; j < 8; ++j) {
        Vt[dq + j][kv] = v0[j];
        Vt[dq + 8 + j][kv] = v1[j];
      }
    }
    __syncthreads();

    // S = (Q K^T) * scale
    floatx4 s[4];
#pragma unroll
    for (int n = 0; n < 4; ++n) {
      const f16* krow = kh + base + (size_t)(kt + n * 16 + li) * DIM;
      half8 kb0 = *(const half8*)(krow + lg * 8);
      half8 kb1 = *(const half8*)(krow + 32 + lg * 8);
      s[n] = __builtin_amdgcn_mfma_f32_16x16x32_f16(qa0, kb0, zero4, 0, 0, 0);
      s[n] = __builtin_amdgcn_mfma_f32_16x16x32_f16(qa1, kb1, s[n], 0, 0, 0);
    }
#pragma unroll
    for (int n = 0; n < 4; ++n) s[n] *= 0.125f;

    // online softmax; lane owns rows lg*4+r; reduce across 16 lanes of group
    float p[4][4];
#pragma unroll
    for (int r = 0; r < 4; ++r) {
      float mx = fmaxf(fmaxf(s[0][r], s[1][r]), fmaxf(s[2][r], s[3][r]));
#pragma unroll
      for (int off = 1; off < 16; off <<= 1)
        mx = fmaxf(mx, __shfl_xor(mx, off));
      const float mnew = fmaxf(mrow[r], mx);
      const float alpha = __expf(mrow[r] - mnew);
      mrow[r] = mnew;
      float rs = 0.f;
#pragma unroll
      for (int n = 0; n < 4; ++n) {
        p[n][r] = __expf(s[n][r] - mnew);
        rs += p[n][r];
      }
#pragma unroll
      for (int off = 1; off < 16; off <<= 1)
        rs += __shfl_xor(rs, off);
      lsum[r] = lsum[r] * alpha + rs;
#pragma unroll
      for (int dt = 0; dt < 4; ++dt) o[dt][r] *= alpha;
    }

    // transpose P via per-wave LDS region (S-layout -> A-fragment layout)
#pragma unroll
    for (int n = 0; n < 4; ++n)
#pragma unroll
      for (int r = 0; r < 4; ++r)
        Pl[wid][lg * 4 + r][n * 16 + li] = (f16)p[n][r];

    half8 pa0 = *(const half8*)&Pl[wid][li][lg * 8];
    half8 pa1 = *(const half8*)&Pl[wid][li][32 + lg * 8];
#pragma unroll
    for (int dt = 0; dt < 4; ++dt) {
      half8 vb0 = *(const half8*)&Vt[dt * 16 + li][lg * 8];
      half8 vb1 = *(const half8*)&Vt[dt * 16 + li][32 + lg * 8];
      o[dt] = __builtin_amdgcn_mfma_f32_16x16x32_f16(pa0, vb0, o[dt], 0, 0, 0);
      o[dt] = __builtin_amdgcn_mfma_f32_16x16x32_f16(pa1, vb1, o[dt], 0, 0, 0);
    }
  }

#pragma unroll
  for (int dt = 0; dt < 4; ++dt)
#pragma unroll
    for (int r = 0; r < 4; ++r) {
      const int row = q0 + lg * 4 + r;
      oh[base + (size_t)row * DIM + dt * 16 + li] = (f16)(o[dt][r] / lsum[r]);
    }
}

extern "C" void kernel_launch(void* const* d_in, const int* in_sizes, int n_in,
                              void* d_out, int out_size, void* d_ws, size_t ws_size,
                              hipStream_t stream)
{
  const float* x  = (const float*)d_in[0];
  const float* Wq = (const float*)d_in[1];
  const float* Wk = (const float*)d_in[2];
  const float* Wv = (const float*)d_in[3];
  const float* Wo = (const float*)d_in[4];
  const float* bo = (const float*)d_in[5];

  char* ws = (char*)d_ws;
  f16* wt   = (f16*)ws;                               // 4 x [1024][1024] fp16 = 8 MB
  f16* qkvh = (f16*)(ws + (size_t)8 * 1024 * 1024);   // 3 x [4096][1024] fp16 = 24 MB
  f16* ohp  = (f16*)(ws + (size_t)32 * 1024 * 1024);  // [4096][1024] fp16 = 8 MB

  k_transpose<<<dim3(32, 32, 4), dim3(32, 8), 0, stream>>>(Wq, Wk, Wv, Wo, wt);

  k_gemm128<true, false><<<dim3(32, 8, 3), 256, 0, stream>>>(
      x, wt, qkvh, nullptr, MTOT, DIM, DIM,
      (size_t)DIM * DIM, (size_t)MTOT * DIM);

  k_attn<<<dim3(32, 32), 256, 0, stream>>>(
      qkvh, qkvh + (size_t)MTOT * DIM, qkvh + (size_t)2 * MTOT * DIM, ohp);

  k_gemm128<false, true><<<dim3(32, 8, 1), 256, 0, stream>>>(
      ohp, wt + (size_t)3 * DIM * DIM, d_out, bo, MTOT, DIM, DIM, 0, 0);
}

// Round 3
// 145.645 us; speedup vs baseline: 1.5793x; 1.5793x over previous
//
#include <hip/hip_runtime.h>
#include <hip/hip_fp16.h>

typedef _Float16 f16;
typedef __attribute__((ext_vector_type(8))) _Float16 half8;
typedef __attribute__((ext_vector_type(2))) __fp16 fp16x2_native;
typedef __attribute__((ext_vector_type(4))) float floatx4;
typedef __attribute__((ext_vector_type(16))) float f32x16;
typedef __attribute__((ext_vector_type(4))) unsigned uint4v;
typedef __attribute__((ext_vector_type(2))) unsigned uint2v;

static constexpr int DIM = 1024;
static constexpr int SEQ = 2048;
static constexpr int DH = 64;
static constexpr int MTOT = 4096;  // BATCH * SEQ

__device__ __forceinline__ float fexp2(float x) {
#if __has_builtin(__builtin_amdgcn_exp2f)
  return __builtin_amdgcn_exp2f(x);
#else
  return exp2f(x);
#endif
}

__device__ __forceinline__ unsigned pkrtz(float a, float b) {
  fp16x2_native h = __builtin_amdgcn_cvt_pkrtz(a, b);
  return __builtin_bit_cast(unsigned, h);
}

__device__ __forceinline__ void pl32swap(unsigned& a, unsigned& b) {
#if __has_builtin(__builtin_amdgcn_permlane32_swap)
  uint2v r = __builtin_amdgcn_permlane32_swap(a, b, false, false);
  a = r.x;
  b = r.y;
#else
  asm volatile("v_permlane32_swap_b32 %0, %1" : "+v"(a), "+v"(b));
#endif
}

// ---- weight transpose + fp16 convert: wt[z][n][k] = W_z[k][n] ----
__global__ __launch_bounds__(256) void k_transpose(
    const float* __restrict__ Wq, const float* __restrict__ Wk,
    const float* __restrict__ Wv, const float* __restrict__ Wo,
    f16* __restrict__ wt)
{
  __shared__ float tile[32][33];
  const int z = blockIdx.z;
  const float* W = (z == 0) ? Wq : (z == 1) ? Wk : (z == 2) ? Wv : Wo;
  f16* out = wt + (size_t)z * DIM * DIM;
  const int tx = threadIdx.x, ty = threadIdx.y;
  const int x0 = blockIdx.x * 32, y0 = blockIdx.y * 32;
#pragma unroll
  for (int i = 0; i < 4; ++i)
    tile[ty + i * 8][tx] = W[(size_t)(y0 + ty + i * 8) * DIM + (x0 + tx)];
  __syncthreads();
#pragma unroll
  for (int i = 0; i < 4; ++i)
    out[(size_t)(x0 + ty + i * 8) * DIM + (y0 + tx)] = (f16)tile[tx][ty + i * 8];
}

// ---- V^T pre-transpose: vt[bh][d][n] = V[b][n][h*64+d] ----
__global__ __launch_bounds__(256) void k_vtrans(
    const f16* __restrict__ vh, f16* __restrict__ vt)
{
  __shared__ f16 T[64][72];
  const int tid = threadIdx.x;
  const int nt = blockIdx.x, bh = blockIdx.y;
  const int b = bh >> 4, h = bh & 15;
  const int n0 = nt * 64;
  const f16* src = vh + (size_t)b * SEQ * DIM + (size_t)h * DH;
#pragma unroll
  for (int i = 0; i < 2; ++i) {
    const int n = (tid >> 3) + i * 32;
    const int cc = tid & 7;
    half8 v = *(const half8*)(src + (size_t)(n0 + n) * DIM + cc * 8);
#pragma unroll
    for (int j = 0; j < 8; ++j) T[cc * 8 + j][n] = v[j];
  }
  __syncthreads();
  f16* dst = vt + (size_t)bh * DH * SEQ;
#pragma unroll
  for (int i = 0; i < 2; ++i) {
    const int d = (tid >> 3) + i * 32;
    const int cc = tid & 7;
    half8 w = *(const half8*)&T[d][cc * 8];
    *(half8*)(dst + (size_t)d * SEQ + n0 + cc * 8) = w;
  }
}

// ---- 128x128-tile fp16 MFMA GEMM: C = A * BT^T (+bias) ----
template <bool A_F32, bool OUT_F32>
__global__ __launch_bounds__(256) void k_gemm128(
    const void* __restrict__ Aptr, const f16* __restrict__ BT,
    void* __restrict__ Cptr, const float* __restrict__ bias,
    int M, int N, int K, size_t bt_zstride, size_t c_zstride)
{
  __shared__ f16 As[128][40];
  __shared__ f16 Bs[128][40];

  const int tid = threadIdx.x;
  const int lane = tid & 63;
  const int wid = tid >> 6;
  const int wr = (wid >> 1) * 64, wc = (wid & 1) * 64;
  const int li = lane & 15, lg = lane >> 4;

  const f16* BTz = BT + (size_t)blockIdx.z * bt_zstride;
  const int row0 = blockIdx.x * 128, col0 = blockIdx.y * 128;
  const int srow = tid >> 1;
  const int shalf = (tid & 1) * 16;

  const floatx4 zero4 = {0.f, 0.f, 0.f, 0.f};
  floatx4 acc[4][4];
#pragma unroll
  for (int m = 0; m < 4; ++m)
#pragma unroll
    for (int n = 0; n < 4; ++n) acc[m][n] = zero4;

  for (int k0 = 0; k0 < K; k0 += 32) {
    __syncthreads();
    if constexpr (A_F32) {
      const float* A = (const float*)Aptr;
      const float4* src = (const float4*)(A + (size_t)(row0 + srow) * K + k0 + shalf);
      float4 v0 = src[0], v1 = src[1], v2 = src[2], v3 = src[3];
      half8 h0 = {(f16)v0.x, (f16)v0.y, (f16)v0.z, (f16)v0.w,
                  (f16)v1.x, (f16)v1.y, (f16)v1.z, (f16)v1.w};
      half8 h1 = {(f16)v2.x, (f16)v2.y, (f16)v2.z, (f16)v2.w,
                  (f16)v3.x, (f16)v3.y, (f16)v3.z, (f16)v3.w};
      *(half8*)&As[srow][shalf] = h0;
      *(half8*)&As[srow][shalf + 8] = h1;
    } else {
      const f16* A = (const f16*)Aptr;
      const f16* src = A + (size_t)(row0 + srow) * K + k0 + shalf;
      *(half8*)&As[srow][shalf] = *(const half8*)src;
      *(half8*)&As[srow][shalf + 8] = *(const half8*)(src + 8);
    }
    {
      const f16* src = BTz + (size_t)(col0 + srow) * K + k0 + shalf;
      *(half8*)&Bs[srow][shalf] = *(const half8*)src;
      *(half8*)&Bs[srow][shalf + 8] = *(const half8*)(src + 8);
    }
    __syncthreads();

    half8 af[4], bf[4];
#pragma unroll
    for (int m = 0; m < 4; ++m)
      af[m] = *(const half8*)&As[wr + m * 16 + li][lg * 8];
#pragma unroll
    for (int n = 0; n < 4; ++n)
      bf[n] = *(const half8*)&Bs[wc + n * 16 + li][lg * 8];
#pragma unroll
    for (int m = 0; m < 4; ++m)
#pragma unroll
      for (int n = 0; n < 4; ++n)
        acc[m][n] = __builtin_amdgcn_mfma_f32_16x16x32_f16(af[m], bf[n], acc[m][n], 0, 0, 0);
  }

#pragma unroll
  for (int m = 0; m < 4; ++m)
#pragma unroll
    for (int n = 0; n < 4; ++n)
#pragma unroll
      for (int r = 0; r < 4; ++r) {
        const int row = row0 + wr + m * 16 + lg * 4 + r;
        const int col = col0 + wc + n * 16 + li;
        if constexpr (OUT_F32) {
          float* C = (float*)Cptr + (size_t)blockIdx.z * c_zstride;
          C[(size_t)row * N + col] = acc[m][n][r] + bias[col];
        } else {
          f16* C = (f16*)Cptr + (size_t)blockIdx.z * c_zstride;
          C[(size_t)row * N + col] = (f16)acc[m][n][r];
        }
      }
}

// ---- flash attention v2: swapped QK^T, 32x32x16 MFMA, in-register softmax ----
__global__ __launch_bounds__(256) void k_attn2(
    const f16* __restrict__ qh, const f16* __restrict__ kh,
    const f16* __restrict__ vt, f16* __restrict__ oh)
{
  __shared__ f16 Ks[64 * 64];   // [kv][d], 16B-col swizzled: c' = c ^ (kv&7)
  __shared__ f16 Vs[64 * 64];   // [d][kv], 16B-col swizzled: c' = c ^ (d&7)
  __shared__ float bc[4][32];   // per-wave q-row broadcast

  const int tid = threadIdx.x;
  const int lane = tid & 63;
  const int wid = tid >> 6;
  const int col = lane & 31;  // q-col in S^T; d-col in O
  const int hi = lane >> 5;

  // XCD-bijective swizzle: 512 blocks, XCD owns 4 consecutive bh
  const int id = blockIdx.x;
  const int xcd = id & 7;
  const int j = id >> 3;
  const int bh = xcd * 4 + (j >> 4);
  const int qi = j & 15;
  const int b = bh >> 4, h = bh & 15;

  const int q0 = qi * 128 + wid * 32;
  const size_t xbase = (size_t)b * SEQ * DIM + (size_t)h * DH;
  const size_t vtbase = (size_t)bh * DH * SEQ;

  const float SC = 0.125f * 1.44269504089f;  // scale * log2(e)
  const float RTRAW = 8.0f / SC;             // defer-max threshold in raw-logit units

  // Q fragments (B-operand): qb[s] holds Q[q0+col][s*16 + hi*8 + 0..7]
  half8 qb[4];
  {
    const f16* qrow = qh + xbase + (size_t)(q0 + col) * DIM;
#pragma unroll
    for (int s = 0; s < 4; ++s) qb[s] = *(const half8*)(qrow + s * 16 + hi * 8);
  }

  f32x16 o0 = {0, 0, 0, 0, 0, 0, 0, 0, 0, 0, 0, 0, 0, 0, 0, 0};
  f32x16 o1 = {0, 0, 0, 0, 0, 0, 0, 0, 0, 0, 0, 0, 0, 0, 0, 0};
  float m = -1e30f, lsum = 0.f;

  for (int kt = 0; kt < SEQ; kt += 64) {
    __syncthreads();
    // stage K (row-major [kv][d]) and V^T ([d][kv]) with swizzled source cols
#pragma unroll
    for (int i = 0; i < 2; ++i) {
      const int s = tid + i * 256;
      const int row = s >> 3, cc = s & 7;
      const int sw = (cc ^ (row & 7)) * 8;
      *(half8*)&Ks[s * 8] = *(const half8*)(kh + xbase + (size_t)(kt + row) * DIM + sw);
      *(half8*)&Vs[s * 8] = *(const half8*)(vt + vtbase + (size_t)row * SEQ + kt + sw);
    }
    __syncthreads();

#pragma unroll
    for (int kvs = 0; kvs < 2; ++kvs) {
      // S^T[kv][q] = K * Q^T via mfma(A=K_frag, B=Q_frag)
      const int krow = kvs * 32 + col;
      f32x16 sacc = {0, 0, 0, 0, 0, 0, 0, 0, 0, 0, 0, 0, 0, 0, 0, 0};
#pragma unroll
      for (int s = 0; s < 4; ++s) {
        const int cc = (2 * s + hi) ^ (krow & 7);
        half8 ka = *(const half8*)&Ks[krow * 64 + cc * 8];
        sacc = __builtin_amdgcn_mfma_f32_32x32x16_f16(ka, qb[s], sacc, 0, 0, 0);
      }

      // in-register row max (lane pair shares q=col)
      float smax = sacc[0];
#pragma unroll
      for (int r = 1; r < 16; ++r) smax = fmaxf(smax, sacc[r]);
      smax = fmaxf(smax, __shfl_xor(smax, 32));

      if (!__all(smax <= m + RTRAW)) {  // rescale (wave-uniform)
        const float mn = fmaxf(m, smax);
        const float alpha = fexp2((m - mn) * SC);
        m = mn;
        lsum *= alpha;
        if (hi == 0) bc[wid][col] = alpha;
#pragma unroll
        for (int r = 0; r < 16; ++r) {
          const float a2 = bc[wid][(r & 3) + 8 * (r >> 2) + 4 * hi];
          o0[r] *= a2;
          o1[r] *= a2;
        }
      }

      const float mc = m * SC;
      float pw[16];
      float rs = 0.f;
#pragma unroll
      for (int r = 0; r < 16; ++r) {
        pw[r] = fexp2(fmaf(sacc[r], SC, -mc));
        rs += pw[r];
      }
      rs += __shfl_xor(rs, 32);
      lsum += rs;

      // P -> fp16 A-fragments in-register (cvt_pkrtz + permlane32_swap)
#pragma unroll
      for (int s2 = 0; s2 < 2; ++s2) {
        const int rb = s2 * 8;
        unsigned X0 = pkrtz(pw[rb + 0], pw[rb + 1]);
        unsigned X1 = pkrtz(pw[rb + 2], pw[rb + 3]);
        unsigned Y0 = pkrtz(pw[rb + 4], pw[rb + 5]);
        unsigned Y1 = pkrtz(pw[rb + 6], pw[rb + 7]);
        pl32swap(X0, Y0);
        pl32swap(X1, Y1);
        const half8 paf = __builtin_bit_cast(half8, (uint4v){X0, X1, Y0, Y1});
        const int kc = kvs * 4 + s2 * 2 + hi;
#pragma unroll
        for (int dt = 0; dt < 2; ++dt) {
          const int vrow = dt * 32 + col;
          const int cc = kc ^ (vrow & 7);
          half8 vb = *(const half8*)&Vs[vrow * 64 + cc * 8];
          if (dt == 0)
            o0 = __builtin_amdgcn_mfma_f32_32x32x16_f16(paf, vb, o0, 0, 0, 0);
          else
            o1 = __builtin_amdgcn_mfma_f32_32x32x16_f16(paf, vb, o1, 0, 0, 0);
        }
      }
    }
  }

  const float inv = 1.0f / lsum;
  if (hi == 0) bc[wid][col] = inv;
#pragma unroll
  for (int r = 0; r < 16; ++r) {
    const int qr = (r & 3) + 8 * (r >> 2) + 4 * hi;
    const float iv = bc[wid][qr];
    f16* orow = oh + xbase + (size_t)(q0 + qr) * DIM;
    orow[col] = (f16)(o0[r] * iv);
    orow[32 + col] = (f16)(o1[r] * iv);
  }
}

extern "C" void kernel_launch(void* const* d_in, const int* in_sizes, int n_in,
                              void* d_out, int out_size, void* d_ws, size_t ws_size,
                              hipStream_t stream)
{
  const float* x  = (const float*)d_in[0];
  const float* Wq = (const float*)d_in[1];
  const float* Wk = (const float*)d_in[2];
  const float* Wv = (const float*)d_in[3];
  const float* Wo = (const float*)d_in[4];
  const float* bo = (const float*)d_in[5];

  char* ws = (char*)d_ws;
  f16* wt   = (f16*)ws;                               // 8 MB
  f16* qkvh = (f16*)(ws + (size_t)8 * 1024 * 1024);   // 24 MB
  f16* ohp  = (f16*)(ws + (size_t)32 * 1024 * 1024);  // 8 MB
  f16* vtb  = (f16*)(ws + (size_t)40 * 1024 * 1024);  // 8 MB

  k_transpose<<<dim3(32, 32, 4), dim3(32, 8), 0, stream>>>(Wq, Wk, Wv, Wo, wt);

  k_gemm128<true, false><<<dim3(32, 8, 3), 256, 0, stream>>>(
      x, wt, qkvh, nullptr, MTOT, DIM, DIM,
      (size_t)DIM * DIM, (size_t)MTOT * DIM);

  k_vtrans<<<dim3(32, 32), 256, 0, stream>>>(
      qkvh + (size_t)2 * MTOT * DIM, vtb);

  k_attn2<<<512, 256, 0, stream>>>(
      qkvh, qkvh + (size_t)MTOT * DIM, vtb, ohp);

  k_gemm128<false, true><<<dim3(32, 8, 1), 256, 0, stream>>>(
      ohp, wt + (size_t)3 * DIM * DIM, d_out, bo, MTOT, DIM, DIM, 0, 0);
}

// Round 4
// 123.981 us; speedup vs baseline: 1.8553x; 1.1747x over previous
//
#include <hip/hip_runtime.h>
#include <hip/hip_fp16.h>

typedef _Float16 f16;
typedef __attribute__((ext_vector_type(8))) _Float16 half8;
typedef __attribute__((ext_vector_type(2))) __fp16 fp16x2_native;
typedef __attribute__((ext_vector_type(4))) float floatx4;
typedef __attribute__((ext_vector_type(16))) float f32x16;
typedef __attribute__((ext_vector_type(4))) unsigned uint4v;
typedef __attribute__((ext_vector_type(2))) unsigned uint2v;

static constexpr int DIM = 1024;
static constexpr int SEQ = 2048;
static constexpr int DH = 64;
static constexpr int MTOT = 4096;  // BATCH * SEQ

__device__ __forceinline__ float fexp2(float x) {
#if __has_builtin(__builtin_amdgcn_exp2f)
  return __builtin_amdgcn_exp2f(x);
#else
  return exp2f(x);
#endif
}

__device__ __forceinline__ unsigned pkrtz(float a, float b) {
  fp16x2_native h = __builtin_amdgcn_cvt_pkrtz(a, b);
  return __builtin_bit_cast(unsigned, h);
}

__device__ __forceinline__ void pl32swap(unsigned& a, unsigned& b) {
#if __has_builtin(__builtin_amdgcn_permlane32_swap)
  uint2v r = __builtin_amdgcn_permlane32_swap(a, b, false, false);
  a = r.x;
  b = r.y;
#else
  asm volatile("v_permlane32_swap_b32 %0, %1" : "+v"(a), "+v"(b));
#endif
}

// async global->LDS 16B (CK-style addrspace reinterpret via uintptr_t)
__device__ __forceinline__ void gll16(const f16* g, f16* l) {
  auto gp = (__attribute__((address_space(1))) unsigned*)(uintptr_t)(const void*)g;
  auto lp = (__attribute__((address_space(3))) unsigned*)(uintptr_t)(void*)l;
  __builtin_amdgcn_global_load_lds(gp, lp, 16, 0, 0);
}

// ---- weight transpose + fp16 convert: wt[z][n][k] = W_z[k][n] ----
__global__ __launch_bounds__(256) void k_transpose(
    const float* __restrict__ Wq, const float* __restrict__ Wk,
    const float* __restrict__ Wv, const float* __restrict__ Wo,
    f16* __restrict__ wt)
{
  __shared__ float tile[32][33];
  const int z = blockIdx.z;
  const float* W = (z == 0) ? Wq : (z == 1) ? Wk : (z == 2) ? Wv : Wo;
  f16* out = wt + (size_t)z * DIM * DIM;
  const int tx = threadIdx.x, ty = threadIdx.y;
  const int x0 = blockIdx.x * 32, y0 = blockIdx.y * 32;
#pragma unroll
  for (int i = 0; i < 4; ++i)
    tile[ty + i * 8][tx] = W[(size_t)(y0 + ty + i * 8) * DIM + (x0 + tx)];
  __syncthreads();
#pragma unroll
  for (int i = 0; i < 4; ++i)
    out[(size_t)(x0 + ty + i * 8) * DIM + (y0 + tx)] = (f16)tile[tx][ty + i * 8];
}

// ---- x fp32 -> fp16 ----
__global__ __launch_bounds__(256) void k_xcast(
    const float* __restrict__ in, f16* __restrict__ out)
{
  const int i = blockIdx.x * 256 + threadIdx.x;
  const float4* p = (const float4*)in;
  float4 a = p[2 * i], b = p[2 * i + 1];
  half8 h = {(f16)a.x, (f16)a.y, (f16)a.z, (f16)a.w,
             (f16)b.x, (f16)b.y, (f16)b.z, (f16)b.w};
  *(half8*)(out + (size_t)i * 8) = h;
}

// ---- V^T pre-transpose: vt[bh][d][n] = V[b][n][h*64+d] ----
__global__ __launch_bounds__(256) void k_vtrans(
    const f16* __restrict__ vh, f16* __restrict__ vt)
{
  __shared__ f16 T[64][72];
  const int tid = threadIdx.x;
  const int nt = blockIdx.x, bh = blockIdx.y;
  const int b = bh >> 4, h = bh & 15;
  const int n0 = nt * 64;
  const f16* src = vh + (size_t)b * SEQ * DIM + (size_t)h * DH;
#pragma unroll
  for (int i = 0; i < 2; ++i) {
    const int n = (tid >> 3) + i * 32;
    const int cc = tid & 7;
    half8 v = *(const half8*)(src + (size_t)(n0 + n) * DIM + cc * 8);
#pragma unroll
    for (int j = 0; j < 8; ++j) T[cc * 8 + j][n] = v[j];
  }
  __syncthreads();
  f16* dst = vt + (size_t)bh * DH * SEQ;
#pragma unroll
  for (int i = 0; i < 2; ++i) {
    const int d = (tid >> 3) + i * 32;
    const int cc = tid & 7;
    half8 w = *(const half8*)&T[d][cc * 8];
    *(half8*)(dst + (size_t)d * SEQ + n0 + cc * 8) = w;
  }
}

// ---- fp16 GEMM, 128x128 tile, BK=32, gll double-buffer, 1 barrier/step ----
// A: [M][K] fp16, BT: [N][K] fp16, C = A*BT^T (+bias)
template <bool OUT_F32>
__global__ __launch_bounds__(256) void k_gemm2(
    const f16* __restrict__ A, const f16* __restrict__ BT,
    void* __restrict__ Cptr, const float* __restrict__ bias,
    int M, int N, int K, size_t bt_zstride, size_t c_zstride)
{
  __shared__ f16 SB[2][8192];  // [buf][ A tile 0..4095 | B tile 4096..8191 ]

  const int tid = threadIdx.x;
  const int lane = tid & 63;
  const int wid = tid >> 6;
  const int wr = (wid >> 1) * 64, wc = (wid & 1) * 64;
  const int li = lane & 15, lg = lane >> 4;

  const f16* BTz = BT + (size_t)blockIdx.z * bt_zstride;
  const int row0 = blockIdx.x * 128, col0 = blockIdx.y * 128;

  // staging: 512 chunks of 16B per tile (128 rows x 4 chunks); 2 per thread
  const int c0 = tid;        // chunk 0..255
  const int c1 = 256 + tid;  // chunk 256..511
  const f16* a0 = A + (size_t)(row0 + (c0 >> 2)) * K + (c0 & 3) * 8;
  const f16* a1 = A + (size_t)(row0 + (c1 >> 2)) * K + (c1 & 3) * 8;
  const f16* b0 = BTz + (size_t)(col0 + (c0 >> 2)) * K + (c0 & 3) * 8;
  const f16* b1 = BTz + (size_t)(col0 + (c1 >> 2)) * K + (c1 & 3) * 8;
  const int da0 = wid * 512, da1 = 2048 + wid * 512;  // wave-uniform dests

  const floatx4 zero4 = {0.f, 0.f, 0.f, 0.f};
  floatx4 acc[4][4];
#pragma unroll
  for (int m = 0; m < 4; ++m)
#pragma unroll
    for (int n = 0; n < 4; ++n) acc[m][n] = zero4;

  auto issue = [&](int buf) {
    gll16(a0, &SB[buf][da0]);
    gll16(a1, &SB[buf][da1]);
    gll16(b0, &SB[buf][4096 + da0]);
    gll16(b1, &SB[buf][4096 + da1]);
    a0 += 32; a1 += 32; b0 += 32; b1 += 32;
  };

  const int nstep = K >> 5;
  issue(0);

  auto step = [&](int buf, int t) {
    asm volatile("s_waitcnt vmcnt(0)" ::: "memory");
    __builtin_amdgcn_s_barrier();
    asm volatile("" ::: "memory");
    if (t + 1 < nstep) issue(buf ^ 1);
    const f16* As = &SB[buf][0];
    const f16* Bs = &SB[buf][4096];
    half8 af[4], bf[4];
#pragma unroll
    for (int m = 0; m < 4; ++m)
      af[m] = *(const half8*)&As[(wr + m * 16 + li) * 32 + lg * 8];
#pragma unroll
    for (int n = 0; n < 4; ++n)
      bf[n] = *(const half8*)&Bs[(wc + n * 16 + li) * 32 + lg * 8];
#pragma unroll
    for (int m = 0; m < 4; ++m)
#pragma unroll
      for (int n = 0; n < 4; ++n)
        acc[m][n] = __builtin_amdgcn_mfma_f32_16x16x32_f16(af[m], bf[n], acc[m][n], 0, 0, 0);
  };

  for (int t2 = 0; t2 < nstep; t2 += 2) {
    step(0, t2);
    step(1, t2 + 1);
  }

#pragma unroll
  for (int m = 0; m < 4; ++m)
#pragma unroll
    for (int n = 0; n < 4; ++n)
#pragma unroll
      for (int r = 0; r < 4; ++r) {
        const int row = row0 + wr + m * 16 + lg * 4 + r;
        const int col = col0 + wc + n * 16 + li;
        if constexpr (OUT_F32) {
          float* C = (float*)Cptr + (size_t)blockIdx.z * c_zstride;
          C[(size_t)row * N + col] = acc[m][n][r] + bias[col];
        } else {
          f16* C = (f16*)Cptr + (size_t)blockIdx.z * c_zstride;
          C[(size_t)row * N + col] = (f16)acc[m][n][r];
        }
      }
}

// ---- flash attention v3: gll double-buffered K/V, 1 barrier/tile ----
__global__ __launch_bounds__(256) void k_attn3(
    const f16* __restrict__ qh, const f16* __restrict__ kh,
    const f16* __restrict__ vt, f16* __restrict__ oh)
{
  __shared__ f16 KV[2][8192];   // [buf][ K 0..4095 | V^T 4096..8191 ], 16B-col swizzled
  __shared__ float bc[4][32];

  const int tid = threadIdx.x;
  const int lane = tid & 63;
  const int wid = tid >> 6;
  const int col = lane & 31;
  const int hi = lane >> 5;

  // XCD-bijective swizzle: 512 blocks, XCD owns 4 consecutive bh
  const int id = blockIdx.x;
  const int xcd = id & 7;
  const int j = id >> 3;
  const int bh = xcd * 4 + (j >> 4);
  const int qi = j & 15;
  const int b = bh >> 4, h = bh & 15;

  const int q0 = qi * 128 + wid * 32;
  const size_t xbase = (size_t)b * SEQ * DIM + (size_t)h * DH;
  const size_t vtbase = (size_t)bh * DH * SEQ;

  const float SC = 0.125f * 1.44269504089f;  // scale * log2(e)
  const float RTRAW = 8.0f / SC;

  // staging: K tile 512 chunks, V tile 512 chunks; 2+2 per thread.
  // physical chunk (row, p) holds logical chunk p ^ (row&7)  (read-side XOR matches)
  const int c0 = tid;
  const int c1 = 256 + tid;
  const int r0 = c0 >> 3, s0 = ((c0 & 7) ^ (r0 & 7)) * 8;
  const int r1 = c1 >> 3, s1 = ((c1 & 7) ^ (r1 & 7)) * 8;
  const f16* ks0 = kh + xbase + (size_t)r0 * DIM + s0;
  const f16* ks1 = kh + xbase + (size_t)r1 * DIM + s1;
  const f16* vs0 = vt + vtbase + (size_t)r0 * SEQ + s0;
  const f16* vs1 = vt + vtbase + (size_t)r1 * SEQ + s1;
  const int dk0 = wid * 512, dk1 = 2048 + wid * 512;

  auto issue = [&](int buf) {
    gll16(ks0, &KV[buf][dk0]);
    gll16(ks1, &KV[buf][dk1]);
    gll16(vs0, &KV[buf][4096 + dk0]);
    gll16(vs1, &KV[buf][4096 + dk1]);
    ks0 += 64 * DIM; ks1 += 64 * DIM; vs0 += 64; vs1 += 64;
  };

  // Q fragments (B-operand)
  half8 qb[4];
  {
    const f16* qrow = qh + xbase + (size_t)(q0 + col) * DIM;
#pragma unroll
    for (int s = 0; s < 4; ++s) qb[s] = *(const half8*)(qrow + s * 16 + hi * 8);
  }

  f32x16 o0 = {0, 0, 0, 0, 0, 0, 0, 0, 0, 0, 0, 0, 0, 0, 0, 0};
  f32x16 o1 = {0, 0, 0, 0, 0, 0, 0, 0, 0, 0, 0, 0, 0, 0, 0, 0};
  float m = -1e30f, lsum = 0.f;

  issue(0);

  auto tile = [&](int buf, int t) {
    asm volatile("s_waitcnt vmcnt(0)" ::: "memory");
    __builtin_amdgcn_s_barrier();
    asm volatile("" ::: "memory");
    if (t < 31) issue(buf ^ 1);
    const f16* Ks = &KV[buf][0];
    const f16* Vs = &KV[buf][4096];

#pragma unroll
    for (int kvs = 0; kvs < 2; ++kvs) {
      const int krow = kvs * 32 + col;
      f32x16 sacc = {0, 0, 0, 0, 0, 0, 0, 0, 0, 0, 0, 0, 0, 0, 0, 0};
      __builtin_amdgcn_s_setprio(1);
#pragma unroll
      for (int s = 0; s < 4; ++s) {
        const int cc = (2 * s + hi) ^ (krow & 7);
        half8 ka = *(const half8*)&Ks[krow * 64 + cc * 8];
        sacc = __builtin_amdgcn_mfma_f32_32x32x16_f16(ka, qb[s], sacc, 0, 0, 0);
      }
      __builtin_amdgcn_s_setprio(0);

      float smax = sacc[0];
#pragma unroll
      for (int r = 1; r < 16; ++r) smax = fmaxf(smax, sacc[r]);
      smax = fmaxf(smax, __shfl_xor(smax, 32));

      if (!__all(smax <= m + RTRAW)) {
        const float mn = fmaxf(m, smax);
        const float alpha = fexp2((m - mn) * SC);
        m = mn;
        lsum *= alpha;
        if (hi == 0) bc[wid][col] = alpha;
#pragma unroll
        for (int r = 0; r < 16; ++r) {
          const float a2 = bc[wid][(r & 3) + 8 * (r >> 2) + 4 * hi];
          o0[r] *= a2;
          o1[r] *= a2;
        }
      }

      const float mc = m * SC;
      float pw[16];
      float rs = 0.f;
#pragma unroll
      for (int r = 0; r < 16; ++r) {
        pw[r] = fexp2(fmaf(sacc[r], SC, -mc));
        rs += pw[r];
      }
      rs += __shfl_xor(rs, 32);
      lsum += rs;

      __builtin_amdgcn_s_setprio(1);
#pragma unroll
      for (int s2 = 0; s2 < 2; ++s2) {
        const int rb = s2 * 8;
        unsigned X0 = pkrtz(pw[rb + 0], pw[rb + 1]);
        unsigned X1 = pkrtz(pw[rb + 2], pw[rb + 3]);
        unsigned Y0 = pkrtz(pw[rb + 4], pw[rb + 5]);
        unsigned Y1 = pkrtz(pw[rb + 6], pw[rb + 7]);
        pl32swap(X0, Y0);
        pl32swap(X1, Y1);
        const half8 paf = __builtin_bit_cast(half8, (uint4v){X0, X1, Y0, Y1});
        const int kc = kvs * 4 + s2 * 2 + hi;
#pragma unroll
        for (int dt = 0; dt < 2; ++dt) {
          const int vrow = dt * 32 + col;
          const int cc = kc ^ (vrow & 7);
          half8 vb = *(const half8*)&Vs[vrow * 64 + cc * 8];
          if (dt == 0)
            o0 = __builtin_amdgcn_mfma_f32_32x32x16_f16(paf, vb, o0, 0, 0, 0);
          else
            o1 = __builtin_amdgcn_mfma_f32_32x32x16_f16(paf, vb, o1, 0, 0, 0);
        }
      }
      __builtin_amdgcn_s_setprio(0);
    }
  };

  for (int t2 = 0; t2 < 32; t2 += 2) {
    tile(0, t2);
    tile(1, t2 + 1);
  }

  const float inv = 1.0f / lsum;
  if (hi == 0) bc[wid][col] = inv;
#pragma unroll
  for (int r = 0; r < 16; ++r) {
    const int qr = (r & 3) + 8 * (r >> 2) + 4 * hi;
    const float iv = bc[wid][qr];
    f16* orow = oh + xbase + (size_t)(q0 + qr) * DIM;
    orow[col] = (f16)(o0[r] * iv);
    orow[32 + col] = (f16)(o1[r] * iv);
  }
}

extern "C" void kernel_launch(void* const* d_in, const int* in_sizes, int n_in,
                              void* d_out, int out_size, void* d_ws, size_t ws_size,
                              hipStream_t stream)
{
  const float* x  = (const float*)d_in[0];
  const float* Wq = (const float*)d_in[1];
  const float* Wk = (const float*)d_in[2];
  const float* Wv = (const float*)d_in[3];
  const float* Wo = (const float*)d_in[4];
  const float* bo = (const float*)d_in[5];

  char* ws = (char*)d_ws;
  f16* wt   = (f16*)ws;                               // 8 MB
  f16* qkvh = (f16*)(ws + (size_t)8 * 1024 * 1024);   // 24 MB
  f16* ohp  = (f16*)(ws + (size_t)32 * 1024 * 1024);  // 8 MB (aliases xh)
  f16* vtb  = (f16*)(ws + (size_t)40 * 1024 * 1024);  // 8 MB
  f16* xh   = ohp;  // x-fp16 consumed by QKV GEMM before attn writes ohp

  k_transpose<<<dim3(32, 32, 4), dim3(32, 8), 0, stream>>>(Wq, Wk, Wv, Wo, wt);

  k_xcast<<<2048, 256, 0, stream>>>(x, xh);

  k_gemm2<false><<<dim3(32, 8, 3), 256, 0, stream>>>(
      xh, wt, qkvh, nullptr, MTOT, DIM, DIM,
      (size_t)DIM * DIM, (size_t)MTOT * DIM);

  k_vtrans<<<dim3(32, 32), 256, 0, stream>>>(
      qkvh + (size_t)2 * MTOT * DIM, vtb);

  k_attn3<<<512, 256, 0, stream>>>(
      qkvh, qkvh + (size_t)MTOT * DIM, vtb, ohp);

  k_gemm2<true><<<dim3(32, 8, 1), 256, 0, stream>>>(
      ohp, wt + (size_t)3 * DIM * DIM, d_out, bo, MTOT, DIM, DIM, 0, 0);
}

// Round 5
// 120.741 us; speedup vs baseline: 1.9051x; 1.0268x over previous
//
#include <hip/hip_runtime.h>
#include <hip/hip_fp16.h>

typedef _Float16 f16;
typedef __attribute__((ext_vector_type(8))) _Float16 half8;
typedef __attribute__((ext_vector_type(2))) __fp16 fp16x2_native;
typedef __attribute__((ext_vector_type(4))) float floatx4;
typedef __attribute__((ext_vector_type(16))) float f32x16;
typedef __attribute__((ext_vector_type(4))) unsigned uint4v;
typedef __attribute__((ext_vector_type(2))) unsigned uint2v;

static constexpr int DIM = 1024;
static constexpr int SEQ = 2048;
static constexpr int DH = 64;
static constexpr int MTOT = 4096;  // BATCH * SEQ

__device__ __forceinline__ float fexp2(float x) {
#if __has_builtin(__builtin_amdgcn_exp2f)
  return __builtin_amdgcn_exp2f(x);
#else
  return exp2f(x);
#endif
}

__device__ __forceinline__ unsigned pkrtz(float a, float b) {
  fp16x2_native h = __builtin_amdgcn_cvt_pkrtz(a, b);
  return __builtin_bit_cast(unsigned, h);
}

__device__ __forceinline__ void pl32swap(unsigned& a, unsigned& b) {
#if __has_builtin(__builtin_amdgcn_permlane32_swap)
  uint2v r = __builtin_amdgcn_permlane32_swap(a, b, false, false);
  a = r.x;
  b = r.y;
#else
  asm volatile("v_permlane32_swap_b32 %0, %1" : "+v"(a), "+v"(b));
#endif
}

// async global->LDS 16B
__device__ __forceinline__ void gll16(const f16* g, f16* l) {
  auto gp = (__attribute__((address_space(1))) unsigned*)(uintptr_t)(const void*)g;
  auto lp = (__attribute__((address_space(3))) unsigned*)(uintptr_t)(void*)l;
  __builtin_amdgcn_global_load_lds(gp, lp, 16, 0, 0);
}

// ---- weight transpose + fp16 convert: wt[z][n][k] = W_z[k][n] ----
__global__ __launch_bounds__(256) void k_transpose(
    const float* __restrict__ Wq, const float* __restrict__ Wk,
    const float* __restrict__ Wv, const float* __restrict__ Wo,
    f16* __restrict__ wt)
{
  __shared__ float tile[32][33];
  const int z = blockIdx.z;
  const float* W = (z == 0) ? Wq : (z == 1) ? Wk : (z == 2) ? Wv : Wo;
  f16* out = wt + (size_t)z * DIM * DIM;
  const int tx = threadIdx.x, ty = threadIdx.y;
  const int x0 = blockIdx.x * 32, y0 = blockIdx.y * 32;
#pragma unroll
  for (int i = 0; i < 4; ++i)
    tile[ty + i * 8][tx] = W[(size_t)(y0 + ty + i * 8) * DIM + (x0 + tx)];
  __syncthreads();
#pragma unroll
  for (int i = 0; i < 4; ++i)
    out[(size_t)(x0 + ty + i * 8) * DIM + (y0 + tx)] = (f16)tile[tx][ty + i * 8];
}

// ---- x fp32 -> fp16 ----
__global__ __launch_bounds__(256) void k_xcast(
    const float* __restrict__ in, f16* __restrict__ out)
{
  const int i = blockIdx.x * 256 + threadIdx.x;
  const float4* p = (const float4*)in;
  float4 a = p[2 * i], b = p[2 * i + 1];
  half8 h = {(f16)a.x, (f16)a.y, (f16)a.z, (f16)a.w,
             (f16)b.x, (f16)b.y, (f16)b.z, (f16)b.w};
  *(half8*)(out + (size_t)i * 8) = h;
}

// ---- V^T pre-transpose: vt[bh][d][n] = V[b][n][h*64+d] ----
__global__ __launch_bounds__(256) void k_vtrans(
    const f16* __restrict__ vh, f16* __restrict__ vt)
{
  __shared__ f16 T[64][72];
  const int tid = threadIdx.x;
  const int nt = blockIdx.x, bh = blockIdx.y;
  const int b = bh >> 4, h = bh & 15;
  const int n0 = nt * 64;
  const f16* src = vh + (size_t)b * SEQ * DIM + (size_t)h * DH;
#pragma unroll
  for (int i = 0; i < 2; ++i) {
    const int n = (tid >> 3) + i * 32;
    const int cc = tid & 7;
    half8 v = *(const half8*)(src + (size_t)(n0 + n) * DIM + cc * 8);
#pragma unroll
    for (int j = 0; j < 8; ++j) T[cc * 8 + j][n] = v[j];
  }
  __syncthreads();
  f16* dst = vt + (size_t)bh * DH * SEQ;
#pragma unroll
  for (int i = 0; i < 2; ++i) {
    const int d = (tid >> 3) + i * 32;
    const int cc = tid & 7;
    half8 w = *(const half8*)&T[d][cc * 8];
    *(half8*)(dst + (size_t)d * SEQ + n0 + cc * 8) = w;
  }
}

// ---- fp16 GEMM, 128x128 tile, BK=32, gll double-buffer, 1 barrier/step ----
template <bool OUT_F32>
__global__ __launch_bounds__(256) void k_gemm2(
    const f16* __restrict__ A, const f16* __restrict__ BT,
    void* __restrict__ Cptr, const float* __restrict__ bias,
    int M, int N, int K, size_t bt_zstride, size_t c_zstride)
{
  __shared__ f16 SB[2][8192];

  const int tid = threadIdx.x;
  const int lane = tid & 63;
  const int wid = tid >> 6;
  const int wr = (wid >> 1) * 64, wc = (wid & 1) * 64;
  const int li = lane & 15, lg = lane >> 4;

  const f16* BTz = BT + (size_t)blockIdx.z * bt_zstride;
  const int row0 = blockIdx.x * 128, col0 = blockIdx.y * 128;

  const int c0 = tid;
  const int c1 = 256 + tid;
  const f16* a0 = A + (size_t)(row0 + (c0 >> 2)) * K + (c0 & 3) * 8;
  const f16* a1 = A + (size_t)(row0 + (c1 >> 2)) * K + (c1 & 3) * 8;
  const f16* b0 = BTz + (size_t)(col0 + (c0 >> 2)) * K + (c0 & 3) * 8;
  const f16* b1 = BTz + (size_t)(col0 + (c1 >> 2)) * K + (c1 & 3) * 8;
  const int da0 = wid * 512, da1 = 2048 + wid * 512;

  const floatx4 zero4 = {0.f, 0.f, 0.f, 0.f};
  floatx4 acc[4][4];
#pragma unroll
  for (int m = 0; m < 4; ++m)
#pragma unroll
    for (int n = 0; n < 4; ++n) acc[m][n] = zero4;

  auto issue = [&](int buf) {
    gll16(a0, &SB[buf][da0]);
    gll16(a1, &SB[buf][da1]);
    gll16(b0, &SB[buf][4096 + da0]);
    gll16(b1, &SB[buf][4096 + da1]);
    a0 += 32; a1 += 32; b0 += 32; b1 += 32;
  };

  const int nstep = K >> 5;
  issue(0);

  auto step = [&](int buf, int t) {
    asm volatile("s_waitcnt vmcnt(0)" ::: "memory");
    __builtin_amdgcn_s_barrier();
    asm volatile("" ::: "memory");
    if (t + 1 < nstep) issue(buf ^ 1);
    const f16* As = &SB[buf][0];
    const f16* Bs = &SB[buf][4096];
    half8 af[4], bf[4];
#pragma unroll
    for (int m = 0; m < 4; ++m)
      af[m] = *(const half8*)&As[(wr + m * 16 + li) * 32 + lg * 8];
#pragma unroll
    for (int n = 0; n < 4; ++n)
      bf[n] = *(const half8*)&Bs[(wc + n * 16 + li) * 32 + lg * 8];
#pragma unroll
    for (int m = 0; m < 4; ++m)
#pragma unroll
      for (int n = 0; n < 4; ++n)
        acc[m][n] = __builtin_amdgcn_mfma_f32_16x16x32_f16(af[m], bf[n], acc[m][n], 0, 0, 0);
  };

  for (int t2 = 0; t2 < nstep; t2 += 2) {
    step(0, t2);
    step(1, t2 + 1);
  }

#pragma unroll
  for (int m = 0; m < 4; ++m)
#pragma unroll
    for (int n = 0; n < 4; ++n)
#pragma unroll
      for (int r = 0; r < 4; ++r) {
        const int row = row0 + wr + m * 16 + lg * 4 + r;
        const int col = col0 + wc + n * 16 + li;
        if constexpr (OUT_F32) {
          float* C = (float*)Cptr + (size_t)blockIdx.z * c_zstride;
          C[(size_t)row * N + col] = acc[m][n][r] + bias[col];
        } else {
          f16* C = (f16*)Cptr + (size_t)blockIdx.z * c_zstride;
          C[(size_t)row * N + col] = (f16)acc[m][n][r];
        }
      }
}

// ---- flash attention v4: 8 waves, intra-block KV split (2 groups of 4),
//      gll double-buffer, LDS merge of (m,l,o) partials ----
__global__ __launch_bounds__(512) void k_attn4(
    const f16* __restrict__ qh, const f16* __restrict__ kh,
    const f16* __restrict__ vt, f16* __restrict__ oh)
{
  __shared__ f16 KV[2][16384];   // [buf][K0|V0|K1|V1] 4096 f16 each, 16B-col swizzled
  __shared__ float bc[8][32];
  __shared__ float Lm[4][32], Ll[4][32], W0[4][32], W1[4][32];

  const int tid = threadIdx.x;
  const int lane = tid & 63;
  const int wid = tid >> 6;   // 0..7
  const int g = wid >> 2;     // kv-half group
  const int sub = wid & 3;    // q-subtile
  const int col = lane & 31;
  const int hi = lane >> 5;

  // XCD-bijective swizzle: 512 blocks, XCD owns 4 consecutive bh
  const int id = blockIdx.x;
  const int xcd = id & 7;
  const int j = id >> 3;
  const int bh = xcd * 4 + (j >> 4);
  const int qi = j & 15;
  const int b = bh >> 4, h = bh & 15;

  const int q0 = qi * 128 + sub * 32;
  const size_t xbase = (size_t)b * SEQ * DIM + (size_t)h * DH;
  const size_t vtbase = (size_t)bh * DH * SEQ;

  const float SC = 0.125f * 1.44269504089f;  // scale * log2(e)
  const float RTRAW = 8.0f / SC;

  // staging: each thread issues 4 gll16/step (K0,V0,K1,V1); 512 thr x 16B = one region
  const int lc = tid & 511;
  const int srow = lc >> 3;
  const int sw = ((lc & 7) ^ (srow & 7)) * 8;
  const f16* ks0 = kh + xbase + (size_t)srow * DIM + sw;
  const f16* ks1 = kh + xbase + (size_t)(1024 + srow) * DIM + sw;
  const f16* vs0 = vt + vtbase + (size_t)srow * SEQ + sw;
  const f16* vs1 = vt + vtbase + (size_t)srow * SEQ + 1024 + sw;

  auto issue = [&](int buf) {
    f16* B = &KV[buf][wid * 512];
    gll16(ks0, B);
    gll16(vs0, B + 4096);
    gll16(ks1, B + 8192);
    gll16(vs1, B + 12288);
    ks0 += 64 * DIM; ks1 += 64 * DIM; vs0 += 64; vs1 += 64;
  };

  // Q fragments (B-operand)
  half8 qb[4];
  {
    const f16* qrow = qh + xbase + (size_t)(q0 + col) * DIM;
#pragma unroll
    for (int s = 0; s < 4; ++s) qb[s] = *(const half8*)(qrow + s * 16 + hi * 8);
  }

  f32x16 o0 = {0, 0, 0, 0, 0, 0, 0, 0, 0, 0, 0, 0, 0, 0, 0, 0};
  f32x16 o1 = {0, 0, 0, 0, 0, 0, 0, 0, 0, 0, 0, 0, 0, 0, 0, 0};
  float m = -1e30f, lsum = 0.f;

  issue(0);

  auto tile = [&](int buf, int t) {
    asm volatile("s_waitcnt vmcnt(0)" ::: "memory");
    __builtin_amdgcn_s_barrier();
    asm volatile("" ::: "memory");
    if (t < 15) issue(buf ^ 1);
    const f16* Ks = &KV[buf][g * 8192];
    const f16* Vs = Ks + 4096;

#pragma unroll
    for (int kvs = 0; kvs < 2; ++kvs) {
      const int krow = kvs * 32 + col;
      f32x16 sacc = {0, 0, 0, 0, 0, 0, 0, 0, 0, 0, 0, 0, 0, 0, 0, 0};
      __builtin_amdgcn_s_setprio(1);
#pragma unroll
      for (int s = 0; s < 4; ++s) {
        const int cc = (2 * s + hi) ^ (krow & 7);
        half8 ka = *(const half8*)&Ks[krow * 64 + cc * 8];
        sacc = __builtin_amdgcn_mfma_f32_32x32x16_f16(ka, qb[s], sacc, 0, 0, 0);
      }
      __builtin_amdgcn_s_setprio(0);

      // tree row-max (max3-fusable, short dep chain)
      float x0 = fmaxf(fmaxf(sacc[0], sacc[1]), fmaxf(sacc[2], sacc[3]));
      float x1 = fmaxf(fmaxf(sacc[4], sacc[5]), fmaxf(sacc[6], sacc[7]));
      float x2 = fmaxf(fmaxf(sacc[8], sacc[9]), fmaxf(sacc[10], sacc[11]));
      float x3 = fmaxf(fmaxf(sacc[12], sacc[13]), fmaxf(sacc[14], sacc[15]));
      float smax = fmaxf(fmaxf(x0, x1), fmaxf(x2, x3));
      smax = fmaxf(smax, __shfl_xor(smax, 32));

      if (!__all(smax <= m + RTRAW)) {
        const float mn = fmaxf(m, smax);
        const float alpha = fexp2((m - mn) * SC);
        m = mn;
        lsum *= alpha;
        if (hi == 0) bc[wid][col] = alpha;
#pragma unroll
        for (int r = 0; r < 16; ++r) {
          const float a2 = bc[wid][(r & 3) + 8 * (r >> 2) + 4 * hi];
          o0[r] *= a2;
          o1[r] *= a2;
        }
      }

      const float mc = m * SC;
      float pw[16];
#pragma unroll
      for (int r = 0; r < 16; ++r) pw[r] = fexp2(fmaf(sacc[r], SC, -mc));
      // tree sum
      float s0 = (pw[0] + pw[1]) + (pw[2] + pw[3]);
      float s1 = (pw[4] + pw[5]) + (pw[6] + pw[7]);
      float s2 = (pw[8] + pw[9]) + (pw[10] + pw[11]);
      float s3 = (pw[12] + pw[13]) + (pw[14] + pw[15]);
      float rs = (s0 + s1) + (s2 + s3);
      rs += __shfl_xor(rs, 32);
      lsum += rs;

      __builtin_amdgcn_s_setprio(1);
#pragma unroll
      for (int s2i = 0; s2i < 2; ++s2i) {
        const int rb = s2i * 8;
        unsigned X0 = pkrtz(pw[rb + 0], pw[rb + 1]);
        unsigned X1 = pkrtz(pw[rb + 2], pw[rb + 3]);
        unsigned Y0 = pkrtz(pw[rb + 4], pw[rb + 5]);
        unsigned Y1 = pkrtz(pw[rb + 6], pw[rb + 7]);
        pl32swap(X0, Y0);
        pl32swap(X1, Y1);
        const half8 paf = __builtin_bit_cast(half8, (uint4v){X0, X1, Y0, Y1});
        const int kc = kvs * 4 + s2i * 2 + hi;
#pragma unroll
        for (int dt = 0; dt < 2; ++dt) {
          const int vrow = dt * 32 + col;
          const int cc = kc ^ (vrow & 7);
          half8 vb = *(const half8*)&Vs[vrow * 64 + cc * 8];
          if (dt == 0)
            o0 = __builtin_amdgcn_mfma_f32_32x32x16_f16(paf, vb, o0, 0, 0, 0);
          else
            o1 = __builtin_amdgcn_mfma_f32_32x32x16_f16(paf, vb, o1, 0, 0, 0);
        }
      }
      __builtin_amdgcn_s_setprio(0);
    }
  };

  for (int t2 = 0; t2 < 16; t2 += 2) {
    tile(0, t2);
    tile(1, t2 + 1);
  }

  // ---- merge the two kv-half partials via LDS ----
  const float inv = 1.0f / lsum;
  if (hi == 0) bc[wid][col] = inv;
  if (g == 1) {
    if (hi == 0) { Lm[sub][col] = m; Ll[sub][col] = lsum; }
    f16* po = &KV[0][0] + sub * 2048;  // 32 rows x 64 cols fp16, normalized
#pragma unroll
    for (int r = 0; r < 16; ++r) {
      const int qr = (r & 3) + 8 * (r >> 2) + 4 * hi;
      const float iv = bc[wid][qr];
      po[qr * 64 + col] = (f16)(o0[r] * iv);
      po[qr * 64 + 32 + col] = (f16)(o1[r] * iv);
    }
  }
  __syncthreads();
  if (g == 0) {
    const float m1 = Lm[sub][col], l1 = Ll[sub][col];
    const float M = fmaxf(m, m1);
    const float e0 = fexp2((m - M) * SC);
    const float a0 = lsum * e0;
    const float a1 = l1 * fexp2((m1 - M) * SC);
    const float rden = 1.0f / (a0 + a1);
    const float c0 = e0 * rden;   // applies to RAW o0
    const float w1 = a1 * rden;   // applies to NORMALIZED o1
    if (hi == 0) { W0[sub][col] = c0; W1[sub][col] = w1; }
    const f16* po = &KV[0][0] + sub * 2048;
#pragma unroll
    for (int r = 0; r < 16; ++r) {
      const int qr = (r & 3) + 8 * (r >> 2) + 4 * hi;
      const float c0r = W0[sub][qr], w1r = W1[sub][qr];
      f16* orow = oh + xbase + (size_t)(q0 + qr) * DIM;
      orow[col] = (f16)(c0r * o0[r] + w1r * (float)po[qr * 64 + col]);
      orow[32 + col] = (f16)(c0r * o1[r] + w1r * (float)po[qr * 64 + 32 + col]);
    }
  }
}

extern "C" void kernel_launch(void* const* d_in, const int* in_sizes, int n_in,
                              void* d_out, int out_size, void* d_ws, size_t ws_size,
                              hipStream_t stream)
{
  const float* x  = (const float*)d_in[0];
  const float* Wq = (const float*)d_in[1];
  const float* Wk = (const float*)d_in[2];
  const float* Wv = (const float*)d_in[3];
  const float* Wo = (const float*)d_in[4];
  const float* bo = (const float*)d_in[5];

  char* ws = (char*)d_ws;
  f16* wt   = (f16*)ws;                               // 8 MB
  f16* qkvh = (f16*)(ws + (size_t)8 * 1024 * 1024);   // 24 MB
  f16* ohp  = (f16*)(ws + (size_t)32 * 1024 * 1024);  // 8 MB (aliases xh)
  f16* vtb  = (f16*)(ws + (size_t)40 * 1024 * 1024);  // 8 MB
  f16* xh   = ohp;  // x-fp16 consumed by QKV GEMM before attn writes ohp

  k_transpose<<<dim3(32, 32, 4), dim3(32, 8), 0, stream>>>(Wq, Wk, Wv, Wo, wt);

  k_xcast<<<2048, 256, 0, stream>>>(x, xh);

  k_gemm2<false><<<dim3(32, 8, 3), 256, 0, stream>>>(
      xh, wt, qkvh, nullptr, MTOT, DIM, DIM,
      (size_t)DIM * DIM, (size_t)MTOT * DIM);

  k_vtrans<<<dim3(32, 32), 256, 0, stream>>>(
      qkvh + (size_t)2 * MTOT * DIM, vtb);

  k_attn4<<<512, 512, 0, stream>>>(
      qkvh, qkvh + (size_t)MTOT * DIM, vtb, ohp);

  k_gemm2<true><<<dim3(32, 8, 1), 256, 0, stream>>>(
      ohp, wt + (size_t)3 * DIM * DIM, d_out, bo, MTOT, DIM, DIM, 0, 0);
}